// Round 1
// baseline (785.077 us; speedup 1.0000x reference)
//
#include <hip/hip_runtime.h>
#include <math.h>

#define T_STEPS 512
#define N_ENVS  256
#define STATE   64
#define HID     128
#define G3      384   // 3*HID gate rows

// One persistent block per env. Thread g owns gate-row g (r rows 0..127,
// z rows 128..255, n rows 256..383). Weight rows live in VGPRs for the
// whole kernel; h and the current x live in LDS and are read as
// wave-uniform broadcast float4s.
__global__ __launch_bounds__(G3, 2) void gru_persist(
    const float* __restrict__ x,      // (T*N, STATE)
    const float* __restrict__ h0,     // (N, HID)
    const float* __restrict__ masks,  // (T*N, 1), values exactly 0.0 or 1.0
    const float* __restrict__ wih,    // (3H, STATE)
    const float* __restrict__ whh,    // (3H, HID)
    const float* __restrict__ bih,    // (3H)
    const float* __restrict__ bhh,    // (3H)
    float* __restrict__ out)          // ys (T*N, H) then h_final (N, H)
{
    const int b = blockIdx.x;   // env
    const int g = threadIdx.x;  // gate row

    __shared__ float hs[HID];    // carried hidden state (unmasked h_{t-1})
    __shared__ float xs[STATE];  // current step's input features
    __shared__ float gg[G3];     // r,z rows: xr+hr / xz+hz ; n rows: xn
    __shared__ float ggn[HID];   // n rows: hn (kept separate for r*hn)

    // ---- persistent weights in registers ----
    float4 wh[HID / 4];
    {
        const float4* p = (const float4*)(whh + g * HID);
#pragma unroll
        for (int i = 0; i < HID / 4; ++i) wh[i] = p[i];
    }
    float4 wi[STATE / 4];
    {
        const float4* p = (const float4*)(wih + g * STATE);
#pragma unroll
        for (int i = 0; i < STATE / 4; ++i) wi[i] = p[i];
    }
    const float bi = bih[g];
    const float bh = bhh[g];

    if (g < HID) hs[g] = h0[b * HID + g];

    // ---- 2-step-ahead prefetch of x and mask (hides HBM latency across
    // the per-step barriers, which drain vmcnt) ----
    float xp0 = 0.f, xp1 = 0.f;
    if (g < STATE) {
        xp0 = x[(0 * N_ENVS + b) * STATE + g];
        xp1 = x[(1 * N_ENVS + b) * STATE + g];
    }
    float mp0 = masks[0 * N_ENVS + b];
    float mp1 = masks[1 * N_ENVS + b];

    for (int t = 0; t < T_STEPS; ++t) {
        // (A) stage current x into LDS
        if (g < STATE) xs[g] = xp0;
        const float m = mp0;
        __syncthreads();  // (B) xs + hs visible to everyone

        // rotate prefetch, issue loads for t+2 (consumed 2 barriers later)
        xp0 = xp1;
        mp0 = mp1;
        if (t + 2 < T_STEPS) {
            if (g < STATE) xp1 = x[((t + 2) * N_ENVS + b) * STATE + g];
            mp1 = masks[(t + 2) * N_ENVS + b];
        }

        // ---- dot products: row g of W_hh . h  and  row g of W_ih . x ----
        const float4* hs4 = (const float4*)hs;
        const float4* xs4 = (const float4*)xs;
        float a0 = 0.f, a1 = 0.f, a2 = 0.f, a3 = 0.f;
#pragma unroll
        for (int i = 0; i < HID / 4; i += 4) {
            float4 v0 = hs4[i + 0], v1 = hs4[i + 1], v2 = hs4[i + 2], v3 = hs4[i + 3];
            a0 = fmaf(wh[i + 0].w, v0.w, fmaf(wh[i + 0].z, v0.z, fmaf(wh[i + 0].y, v0.y, fmaf(wh[i + 0].x, v0.x, a0))));
            a1 = fmaf(wh[i + 1].w, v1.w, fmaf(wh[i + 1].z, v1.z, fmaf(wh[i + 1].y, v1.y, fmaf(wh[i + 1].x, v1.x, a1))));
            a2 = fmaf(wh[i + 2].w, v2.w, fmaf(wh[i + 2].z, v2.z, fmaf(wh[i + 2].y, v2.y, fmaf(wh[i + 2].x, v2.x, a2))));
            a3 = fmaf(wh[i + 3].w, v3.w, fmaf(wh[i + 3].z, v3.z, fmaf(wh[i + 3].y, v3.y, fmaf(wh[i + 3].x, v3.x, a3))));
        }
        const float hh_raw = (a0 + a1) + (a2 + a3);

        float c0 = 0.f, c1 = 0.f, c2 = 0.f, c3 = 0.f;
#pragma unroll
        for (int i = 0; i < STATE / 4; i += 4) {
            float4 v0 = xs4[i + 0], v1 = xs4[i + 1], v2 = xs4[i + 2], v3 = xs4[i + 3];
            c0 = fmaf(wi[i + 0].w, v0.w, fmaf(wi[i + 0].z, v0.z, fmaf(wi[i + 0].y, v0.y, fmaf(wi[i + 0].x, v0.x, c0))));
            c1 = fmaf(wi[i + 1].w, v1.w, fmaf(wi[i + 1].z, v1.z, fmaf(wi[i + 1].y, v1.y, fmaf(wi[i + 1].x, v1.x, c1))));
            c2 = fmaf(wi[i + 2].w, v2.w, fmaf(wi[i + 2].z, v2.z, fmaf(wi[i + 2].y, v2.y, fmaf(wi[i + 2].x, v2.x, c2))));
            c3 = fmaf(wi[i + 3].w, v3.w, fmaf(wi[i + 3].z, v3.z, fmaf(wi[i + 3].y, v3.y, fmaf(wi[i + 3].x, v3.x, c3))));
        }
        const float xg = ((c0 + c1) + (c2 + c3)) + bi;       // x-projection + bias_ih
        const float hg = fmaf(m, hh_raw, bh);                // m*(W_hh.h) + bias_hh  (m exact 0/1)

        if (g < 2 * HID) {
            gg[g] = xg + hg;            // u_r or u_z
        } else {
            gg[g] = xg;                 // xn (incl. bias_ih)
            ggn[g - 2 * HID] = hg;      // hn (incl. bias_hh) — multiplied by r later
        }
        __syncthreads();  // (D) gates visible; all hs reads done

        // ---- gate math + state update (threads 0..127) ----
        if (g < HID) {
            const float ur = gg[g];
            const float uz = gg[HID + g];
            const float xn = gg[2 * HID + g];
            const float hn = ggn[g];
            const float r = __builtin_amdgcn_rcpf(1.f + __expf(-ur));
            const float z = __builtin_amdgcn_rcpf(1.f + __expf(-uz));
            const float a = fmaf(r, hn, xn);
            // tanh via exp, overflow-safe
            const float e = __expf(-2.f * fabsf(a));
            const float mag = (1.f - e) * __builtin_amdgcn_rcpf(1.f + e);
            const float cand = copysignf(mag, a);
            const float hm = m * hs[g];
            const float hnew = fmaf(z, hm - cand, cand);  // (1-z)*cand + z*hm
            hs[g] = hnew;
            out[(t * N_ENVS + b) * HID + g] = hnew;
        }
        // next (B) barrier makes hs/xs updates visible before the next dots
    }

    __syncthreads();
    if (g < HID) out[T_STEPS * N_ENVS * HID + b * HID + g] = hs[g];
}

extern "C" void kernel_launch(void* const* d_in, const int* in_sizes, int n_in,
                              void* d_out, int out_size, void* d_ws, size_t ws_size,
                              hipStream_t stream) {
    const float* x    = (const float*)d_in[0];
    const float* h0   = (const float*)d_in[1];
    const float* mk   = (const float*)d_in[2];
    const float* wih  = (const float*)d_in[3];
    const float* whh  = (const float*)d_in[4];
    const float* bih  = (const float*)d_in[5];
    const float* bhh  = (const float*)d_in[6];
    float* out = (float*)d_out;

    hipLaunchKernelGGL(gru_persist, dim3(N_ENVS), dim3(G3), 0, stream,
                       x, h0, mk, wih, whh, bih, bhh, out);
}

// Round 2
// 766.246 us; speedup vs baseline: 1.0246x; 1.0246x over previous
//
#include <hip/hip_runtime.h>
#include <math.h>

#define T_STEPS 512
#define N_ENVS  256
#define STATE   64
#define HID     128
#define G3      384   // 3*HID gate rows
#define RING    16    // steps buffered in LDS before a bulk global flush

// One persistent block per env. Thread g owns gate-row g (r rows 0..127,
// z rows 128..255, n rows 256..383). Weight rows live in VGPRs for the
// whole kernel; h and the current x live in LDS and are read as
// wave-uniform broadcast float4s.
//
// R2: outputs are staged in an LDS ring (RING steps) and flushed to HBM in
// bulk once per RING steps, so the compiler's `s_waitcnt vmcnt(0)` before
// each s_barrier no longer drains a fresh HBM store every step (was ~900
// cyc/step on the critical chain). h also carried in a register in the
// update threads to shorten the phase-2 LDS chain.
__global__ __launch_bounds__(G3, 2) void gru_persist(
    const float* __restrict__ x,      // (T*N, STATE)
    const float* __restrict__ h0,     // (N, HID)
    const float* __restrict__ masks,  // (T*N, 1), values exactly 0.0 or 1.0
    const float* __restrict__ wih,    // (3H, STATE)
    const float* __restrict__ whh,    // (3H, HID)
    const float* __restrict__ bih,    // (3H)
    const float* __restrict__ bhh,    // (3H)
    float* __restrict__ out)          // ys (T*N, H) then h_final (N, H)
{
    const int b = blockIdx.x;   // env
    const int g = threadIdx.x;  // gate row

    __shared__ float hs[HID];    // carried hidden state (unmasked h_{t-1})
    __shared__ float xs[STATE];  // current step's input features
    __shared__ float gg[G3];     // r,z rows: xr+hr / xz+hz ; n rows: xn
    __shared__ float ggn[HID];   // n rows: hn (kept separate for r*hn)
    __shared__ __align__(16) float ring[RING * HID];  // output staging

    // ---- persistent weights in registers ----
    float4 wh[HID / 4];
    {
        const float4* p = (const float4*)(whh + g * HID);
#pragma unroll
        for (int i = 0; i < HID / 4; ++i) wh[i] = p[i];
    }
    float4 wi[STATE / 4];
    {
        const float4* p = (const float4*)(wih + g * STATE);
#pragma unroll
        for (int i = 0; i < STATE / 4; ++i) wi[i] = p[i];
    }
    const float bi = bih[g];
    const float bh = bhh[g];

    float hold = 0.f;  // register copy of h_j for update threads (g < HID)
    if (g < HID) {
        hold = h0[b * HID + g];
        hs[g] = hold;
    }

    // ---- 2-step-ahead prefetch of x and mask ----
    float xp0 = 0.f, xp1 = 0.f;
    if (g < STATE) {
        xp0 = x[(0 * N_ENVS + b) * STATE + g];
        xp1 = x[(1 * N_ENVS + b) * STATE + g];
    }
    float mp0 = masks[0 * N_ENVS + b];
    float mp1 = masks[1 * N_ENVS + b];

    for (int t = 0; t < T_STEPS; ++t) {
        // (A) stage current x into LDS
        if (g < STATE) xs[g] = xp0;
        const float m = mp0;
        __syncthreads();  // (B) xs + hs (+ previous phase-2 ring writes) visible

        // bulk flush of the previous RING steps' outputs (issued here, drained
        // at barrier D — ~400 cyc of FMA phase hides most of the store ack)
        if ((t & (RING - 1)) == 0 && t != 0) {
            const int tbase = t - RING;
            const float4* r4 = (const float4*)ring;
            for (int u = g; u < RING * (HID / 4); u += G3) {
                const int k  = u >> 5;   // step within chunk
                const int j4 = u & 31;   // float4 index within row
                float4* dst = (float4*)(out + ((size_t)(tbase + k) * N_ENVS + b) * HID);
                dst[j4] = r4[k * 32 + j4];
            }
        }

        // rotate prefetch, issue loads for t+2 (consumed 2 barriers later)
        xp0 = xp1;
        mp0 = mp1;
        if (t + 2 < T_STEPS) {
            if (g < STATE) xp1 = x[((t + 2) * N_ENVS + b) * STATE + g];
            mp1 = masks[(t + 2) * N_ENVS + b];
        }

        // ---- dot products: row g of W_hh . h  and  row g of W_ih . x ----
        const float4* hs4 = (const float4*)hs;
        const float4* xs4 = (const float4*)xs;
        float a0 = 0.f, a1 = 0.f, a2 = 0.f, a3 = 0.f;
#pragma unroll
        for (int i = 0; i < HID / 4; i += 4) {
            float4 v0 = hs4[i + 0], v1 = hs4[i + 1], v2 = hs4[i + 2], v3 = hs4[i + 3];
            a0 = fmaf(wh[i + 0].w, v0.w, fmaf(wh[i + 0].z, v0.z, fmaf(wh[i + 0].y, v0.y, fmaf(wh[i + 0].x, v0.x, a0))));
            a1 = fmaf(wh[i + 1].w, v1.w, fmaf(wh[i + 1].z, v1.z, fmaf(wh[i + 1].y, v1.y, fmaf(wh[i + 1].x, v1.x, a1))));
            a2 = fmaf(wh[i + 2].w, v2.w, fmaf(wh[i + 2].z, v2.z, fmaf(wh[i + 2].y, v2.y, fmaf(wh[i + 2].x, v2.x, a2))));
            a3 = fmaf(wh[i + 3].w, v3.w, fmaf(wh[i + 3].z, v3.z, fmaf(wh[i + 3].y, v3.y, fmaf(wh[i + 3].x, v3.x, a3))));
        }
        const float hh_raw = (a0 + a1) + (a2 + a3);

        float c0 = 0.f, c1 = 0.f, c2 = 0.f, c3 = 0.f;
#pragma unroll
        for (int i = 0; i < STATE / 4; i += 4) {
            float4 v0 = xs4[i + 0], v1 = xs4[i + 1], v2 = xs4[i + 2], v3 = xs4[i + 3];
            c0 = fmaf(wi[i + 0].w, v0.w, fmaf(wi[i + 0].z, v0.z, fmaf(wi[i + 0].y, v0.y, fmaf(wi[i + 0].x, v0.x, c0))));
            c1 = fmaf(wi[i + 1].w, v1.w, fmaf(wi[i + 1].z, v1.z, fmaf(wi[i + 1].y, v1.y, fmaf(wi[i + 1].x, v1.x, c1))));
            c2 = fmaf(wi[i + 2].w, v2.w, fmaf(wi[i + 2].z, v2.z, fmaf(wi[i + 2].y, v2.y, fmaf(wi[i + 2].x, v2.x, c2))));
            c3 = fmaf(wi[i + 3].w, v3.w, fmaf(wi[i + 3].z, v3.z, fmaf(wi[i + 3].y, v3.y, fmaf(wi[i + 3].x, v3.x, c3))));
        }
        const float xg = ((c0 + c1) + (c2 + c3)) + bi;       // x-projection + bias_ih
        const float hg = fmaf(m, hh_raw, bh);                // m*(W_hh.h) + bias_hh  (m exact 0/1)

        if (g < 2 * HID) {
            gg[g] = xg + hg;            // u_r or u_z
        } else {
            gg[g] = xg;                 // xn (incl. bias_ih)
            ggn[g - 2 * HID] = hg;      // hn (incl. bias_hh) — multiplied by r later
        }
        __syncthreads();  // (D) gates visible; all hs/ring reads done

        // ---- gate math + state update (threads 0..127) ----
        if (g < HID) {
            const float ur = gg[g];
            const float uz = gg[HID + g];
            const float xn = gg[2 * HID + g];
            const float hn = ggn[g];
            const float r = __builtin_amdgcn_rcpf(1.f + __expf(-ur));
            const float z = __builtin_amdgcn_rcpf(1.f + __expf(-uz));
            const float a = fmaf(r, hn, xn);
            // tanh via exp, overflow-safe
            const float e = __expf(-2.f * fabsf(a));
            const float mag = (1.f - e) * __builtin_amdgcn_rcpf(1.f + e);
            const float cand = copysignf(mag, a);
            const float hm = m * hold;
            const float hnew = fmaf(z, hm - cand, cand);  // (1-z)*cand + z*hm
            hold = hnew;
            hs[g] = hnew;
            ring[(t & (RING - 1)) * HID + g] = hnew;
        }
        // next (B) barrier makes hs/xs/ring updates visible
    }

    __syncthreads();
    // flush the final RING chunk (steps T-RING .. T-1)
    {
        const int tbase = T_STEPS - RING;
        const float4* r4 = (const float4*)ring;
        for (int u = g; u < RING * (HID / 4); u += G3) {
            const int k  = u >> 5;
            const int j4 = u & 31;
            float4* dst = (float4*)(out + ((size_t)(tbase + k) * N_ENVS + b) * HID);
            dst[j4] = r4[k * 32 + j4];
        }
    }
    if (g < HID) out[(size_t)T_STEPS * N_ENVS * HID + b * HID + g] = hold;
}

extern "C" void kernel_launch(void* const* d_in, const int* in_sizes, int n_in,
                              void* d_out, int out_size, void* d_ws, size_t ws_size,
                              hipStream_t stream) {
    const float* x    = (const float*)d_in[0];
    const float* h0   = (const float*)d_in[1];
    const float* mk   = (const float*)d_in[2];
    const float* wih  = (const float*)d_in[3];
    const float* whh  = (const float*)d_in[4];
    const float* bih  = (const float*)d_in[5];
    const float* bhh  = (const float*)d_in[6];
    float* out = (float*)d_out;

    hipLaunchKernelGGL(gru_persist, dim3(N_ENVS), dim3(G3), 0, stream,
                       x, h0, mk, wih, whh, bih, bhh, out);
}

// Round 3
// 436.006 us; speedup vs baseline: 1.8006x; 1.7574x over previous
//
#include <hip/hip_runtime.h>
#include <math.h>

#define T_STEPS  512
#define N_ENVS   256
#define STATE    64
#define HID      128
#define NTHREADS 256   // 4 waves

typedef _Float16 half8  __attribute__((ext_vector_type(8)));
typedef _Float16 half4_t __attribute__((ext_vector_type(4)));
typedef float    floatx4 __attribute__((ext_vector_type(4)));

__device__ __forceinline__ float sigmoid_fast(float v) {
    return __builtin_amdgcn_rcpf(1.f + __expf(-v));
}
__device__ __forceinline__ float tanh_fast(float v) {
    const float e  = __expf(-2.f * fabsf(v));
    const float mg = (1.f - e) * __builtin_amdgcn_rcpf(1.f + e);
    return copysignf(mg, v);
}

// One block per env, 4 waves. Wave w owns gate tiles: r:{2w,2w+1}, z:{8+2w,9+2w},
// n:{16+2w,17+2w}. Weights live as 36 f16 MFMA B-fragments in VGPRs. The state
// vector [h;x] (192 f16) is broadcast from LDS as A-fragments (all rows equal,
// making the result independent of A's m/k lane mapping). Gate math is done in
// registers: lane c of wave w owns hidden units j0=32w+c, j1=j0+16.
// One barrier per step; x/mask loads and output flushes batched per 16 steps.
__global__ __launch_bounds__(NTHREADS, 1) void gru_mfma(
    const float* __restrict__ x,      // (T*N, STATE)
    const float* __restrict__ h0,     // (N, HID)
    const float* __restrict__ masks,  // (T*N, 1) in {0,1}
    const float* __restrict__ wih,    // (3H, STATE)
    const float* __restrict__ whh,    // (3H, HID)
    const float* __restrict__ bih,    // (3H)
    const float* __restrict__ bhh,    // (3H)
    float* __restrict__ out)          // ys (T*N,H) then h_final (N,H)
{
    const int b    = blockIdx.x;
    const int tid  = threadIdx.x;
    const int w    = tid >> 6;
    const int lane = tid & 63;
    const int c    = lane & 15;
    const int quad = lane >> 4;
    const int j0   = 32 * w + c;
    const int j1   = j0 + 16;

    __shared__ __align__(16) _Float16 buf[2][192];          // [h(128); x(64)] f16, dbuf by step parity
    __shared__ __align__(16) float    xstage[2][16][STATE]; // fp32 x staged per 16-step chunk
    __shared__ __align__(16) float    ring[2][16][HID];     // output ring, dbuf by chunk parity
    __shared__ float ms[32];                                // masks, rolling window

    // ---- persistent B-fragments (weights), f16, 36 x 4 VGPRs ----
    const int nt[6] = {2*w, 2*w + 1, 8 + 2*w, 9 + 2*w, 16 + 2*w, 17 + 2*w};
    half8 B[6][6];
#pragma unroll
    for (int ti = 0; ti < 6; ++ti) {
        const int g = nt[ti] * 16 + c;
#pragma unroll
        for (int kt = 0; kt < 6; ++kt) {
            const float* src = (kt < 4) ? (whh + (size_t)g * HID + kt * 32 + quad * 8)
                                        : (wih + (size_t)g * STATE + (kt - 4) * 32 + quad * 8);
            const float4 p0 = *(const float4*)(src);
            const float4 p1 = *(const float4*)(src + 4);
            half8 hb;
            hb[0] = (_Float16)p0.x; hb[1] = (_Float16)p0.y;
            hb[2] = (_Float16)p0.z; hb[3] = (_Float16)p0.w;
            hb[4] = (_Float16)p1.x; hb[5] = (_Float16)p1.y;
            hb[6] = (_Float16)p1.z; hb[7] = (_Float16)p1.w;
            B[ti][kt] = hb;
        }
    }

    // ---- biases for this lane's two hidden units ----
    const float brz0 = bih[j0] + bhh[j0];
    const float brz1 = bih[j1] + bhh[j1];
    const float brz2 = bih[HID + j0] + bhh[HID + j0];
    const float brz3 = bih[HID + j1] + bhh[HID + j1];
    const float bhn0 = bhh[2 * HID + j0], bhn1 = bhh[2 * HID + j1];
    const float bxn0 = bih[2 * HID + j0], bxn1 = bih[2 * HID + j1];

    // ---- state preload ----
    float hr0 = h0[(size_t)b * HID + j0];
    float hr1 = h0[(size_t)b * HID + j1];
    const float m0 = masks[b];
    float hm0 = m0 * hr0, hm1 = m0 * hr1;

    // xstage[0] <- x for steps 1..16 (step 17+ loaded at chunk starts)
    if (lane < 16) {
#pragma unroll
        for (int r = 0; r < 4; ++r) {
            const int st = 1 + 4 * w + r;
            *(float4*)&xstage[0][4 * w + r][4 * c] =
                *(const float4*)(x + ((size_t)st * N_ENVS + b) * STATE + 4 * c);
        }
        if (w == 0) {
            // x_0 directly into buf[0]
            const float4 xv = *(const float4*)(x + (size_t)b * STATE + 4 * c);
            half4_t hx = {(_Float16)xv.x, (_Float16)xv.y, (_Float16)xv.z, (_Float16)xv.w};
            *(half4_t*)&buf[0][128 + 4 * c] = hx;
            ms[c] = masks[(size_t)c * N_ENVS + b];   // masks for steps 0..15
        }
        buf[0][j0] = (_Float16)hm0;   // masked h_0 input
        buf[0][j1] = (_Float16)hm1;
    }
    float mreg = masks[(size_t)(16 + c) * N_ENVS + b];   // masks for steps 16..31
    __syncthreads();

    const floatx4 zero4 = {0.f, 0.f, 0.f, 0.f};

    for (int tc = 0; tc < 32; ++tc) {
#pragma unroll
        for (int s = 0; s < 16; ++s) {
            const int t = tc * 16 + s;
            const _Float16* bufc = buf[s & 1];           // s&1 == t&1 (chunks are 16 long)
            _Float16* bufn = (_Float16*)buf[(s + 1) & 1];

            // ---- A fragments: broadcast [h;x] (same 16B across each quad-group) ----
            half8 a[6];
#pragma unroll
            for (int kt = 0; kt < 6; ++kt)
                a[kt] = *(const half8*)(bufc + kt * 32 + quad * 8);

            // ---- 36 MFMAs, 6 independent accumulator streams ----
            floatx4 arz0, arz1, arz2, arz3, ahn0, ahn1, axn0, axn1;
#pragma unroll
            for (int kt = 0; kt < 6; ++kt) {
                arz0 = __builtin_amdgcn_mfma_f32_16x16x32_f16(a[kt], B[0][kt], kt == 0 ? zero4 : arz0, 0, 0, 0);
                arz1 = __builtin_amdgcn_mfma_f32_16x16x32_f16(a[kt], B[1][kt], kt == 0 ? zero4 : arz1, 0, 0, 0);
                arz2 = __builtin_amdgcn_mfma_f32_16x16x32_f16(a[kt], B[2][kt], kt == 0 ? zero4 : arz2, 0, 0, 0);
                arz3 = __builtin_amdgcn_mfma_f32_16x16x32_f16(a[kt], B[3][kt], kt == 0 ? zero4 : arz3, 0, 0, 0);
                if (kt < 4) {
                    ahn0 = __builtin_amdgcn_mfma_f32_16x16x32_f16(a[kt], B[4][kt], kt == 0 ? zero4 : ahn0, 0, 0, 0);
                    ahn1 = __builtin_amdgcn_mfma_f32_16x16x32_f16(a[kt], B[5][kt], kt == 0 ? zero4 : ahn1, 0, 0, 0);
                } else {
                    axn0 = __builtin_amdgcn_mfma_f32_16x16x32_f16(a[kt], B[4][kt], kt == 4 ? zero4 : axn0, 0, 0, 0);
                    axn1 = __builtin_amdgcn_mfma_f32_16x16x32_f16(a[kt], B[5][kt], kt == 4 ? zero4 : axn1, 0, 0, 0);
                }
            }

            // ---- chunk-start batched VMEM (one drain event per 16 steps) ----
            if (s == 0) {
                if (tc > 0) {   // flush previous chunk's outputs
                    const int q = (tc - 1) & 1;
                    const int tb = (tc - 1) * 16;
#pragma unroll
                    for (int u0 = 0; u0 < 2; ++u0) {
                        const int u = tid + u0 * NTHREADS;
                        const int k = u >> 5, jj = (u & 31) * 4;
                        *(float4*)(out + ((size_t)(tb + k) * N_ENVS + b) * HID + jj) =
                            *(const float4*)&ring[q][k][jj];
                    }
                }
                if (w == 0 && lane < 16) ms[(tc * 16 + 16 + c) & 31] = mreg;  // masks [tb+16, tb+32)
                {
                    const int stm = tc * 16 + 32 + c;
                    if (stm < T_STEPS) mreg = masks[(size_t)stm * N_ENVS + b];
                }
                if (lane < 16) {   // x batch for chunk tc+1
#pragma unroll
                    for (int r = 0; r < 4; ++r) {
                        const int st = tc * 16 + 17 + 4 * w + r;
                        if (st < T_STEPS)
                            *(float4*)&xstage[(tc + 1) & 1][4 * w + r][4 * c] =
                                *(const float4*)(x + ((size_t)st * N_ENVS + b) * STATE + 4 * c);
                    }
                }
            }

            // ---- gate math in registers (all D rows equal; read acc elem 0) ----
            const float pr0 = arz0[0] + brz0;
            const float pr1 = arz1[0] + brz1;
            const float pz0 = arz2[0] + brz2;
            const float pz1 = arz3[0] + brz3;
            const float hn0 = ahn0[0] + bhn0;
            const float hn1 = ahn1[0] + bhn1;
            const float xn0 = axn0[0] + bxn0;
            const float xn1 = axn1[0] + bxn1;
            const float r0 = sigmoid_fast(pr0), r1 = sigmoid_fast(pr1);
            const float z0 = sigmoid_fast(pz0), z1 = sigmoid_fast(pz1);
            const float cd0 = tanh_fast(fmaf(r0, hn0, xn0));
            const float cd1 = tanh_fast(fmaf(r1, hn1, xn1));
            const float hnew0 = fmaf(z0, hm0 - cd0, cd0);   // (1-z)*cand + z*(m*h)
            const float hnew1 = fmaf(z1, hm1 - cd1, cd1);

            if (lane < 16) {
                ring[tc & 1][s][j0] = hnew0;
                ring[tc & 1][s][j1] = hnew1;
            }
            if (t < T_STEPS - 1) {
                const float mn = ms[(t + 1) & 31];
                hm0 = mn * hnew0;
                hm1 = mn * hnew1;
                if (lane < 16) {
                    bufn[j0] = (_Float16)hm0;   // masked h for next step's A
                    bufn[j1] = (_Float16)hm1;
                    if (w == (s & 3)) {         // x_{t+1} f16 into next buf
                        const float4 xv = *(const float4*)&xstage[tc & 1][s][4 * c];
                        half4_t hx = {(_Float16)xv.x, (_Float16)xv.y, (_Float16)xv.z, (_Float16)xv.w};
                        *(half4_t*)&bufn[128 + 4 * c] = hx;
                    }
                }
            }
            hr0 = hnew0;
            hr1 = hnew1;
            __syncthreads();
        }
    }

    // final flush: chunk 31 (ring parity 1, steps 496..511)
#pragma unroll
    for (int u0 = 0; u0 < 2; ++u0) {
        const int u = tid + u0 * NTHREADS;
        const int k = u >> 5, jj = (u & 31) * 4;
        *(float4*)(out + ((size_t)(496 + k) * N_ENVS + b) * HID + jj) =
            *(const float4*)&ring[1][k][jj];
    }
    if (lane < 16) {
        out[(size_t)T_STEPS * N_ENVS * HID + (size_t)b * HID + j0] = hr0;
        out[(size_t)T_STEPS * N_ENVS * HID + (size_t)b * HID + j1] = hr1;
    }
}

extern "C" void kernel_launch(void* const* d_in, const int* in_sizes, int n_in,
                              void* d_out, int out_size, void* d_ws, size_t ws_size,
                              hipStream_t stream) {
    const float* x   = (const float*)d_in[0];
    const float* h0  = (const float*)d_in[1];
    const float* mk  = (const float*)d_in[2];
    const float* wih = (const float*)d_in[3];
    const float* whh = (const float*)d_in[4];
    const float* bih = (const float*)d_in[5];
    const float* bhh = (const float*)d_in[6];
    float* out = (float*)d_out;

    hipLaunchKernelGGL(gru_mfma, dim3(N_ENVS), dim3(NTHREADS), 0, stream,
                       x, h0, mk, wih, whh, bih, bhh, out);
}

// Round 4
// 338.022 us; speedup vs baseline: 2.3226x; 1.2899x over previous
//
#include <hip/hip_runtime.h>
#include <math.h>

#define T_STEPS  512
#define N_ENVS   256
#define STATE    64
#define HID      128
#define NTHREADS 512   // 8 waves

typedef _Float16 half8   __attribute__((ext_vector_type(8)));
typedef _Float16 half2_t __attribute__((ext_vector_type(2)));
typedef float    floatx4 __attribute__((ext_vector_type(4)));

__device__ __forceinline__ float sigmoid_fast(float v) {
    return __builtin_amdgcn_rcpf(1.f + __expf(-v));
}
__device__ __forceinline__ float tanh_fast(float v) {
    const float e  = __expf(-2.f * fabsf(v));
    const float mg = (1.f - e) * __builtin_amdgcn_rcpf(1.f + e);
    return copysignf(mg, v);
}

// One block per env, 8 waves. Wave w owns row-tiles r:{w}, z:{8+w}, n:{16+w};
// lane c of wave w owns hidden unit j = 16w + c (one unit per lane -> 3
// transcendentals per step, vs 6 in the 4-wave version). Weights are 18 f16
// B-fragments per wave in registers. State [h;x] (192 f16) broadcast from LDS
// as A-fragments (all 16 rows equal -> result independent of A row mapping;
// D value read from acc elem 0, col = lane&15 — validated in R3).
// 2 waves/SIMD so co-resident waves interleave exposed latencies.
// One barrier per step; all VMEM batched at 16-step chunk boundaries, with x
// prefetched into registers a full chunk ahead of its LDS write.
__global__ __launch_bounds__(NTHREADS, 2) void gru_mfma8(
    const float* __restrict__ x,      // (T*N, STATE)
    const float* __restrict__ h0,     // (N, HID)
    const float* __restrict__ masks,  // (T*N, 1) in {0,1}
    const float* __restrict__ wih,    // (3H, STATE)
    const float* __restrict__ whh,    // (3H, HID)
    const float* __restrict__ bih,    // (3H)
    const float* __restrict__ bhh,    // (3H)
    float* __restrict__ out)          // ys (T*N,H) then h_final (N,H)
{
    const int b    = blockIdx.x;
    const int tid  = threadIdx.x;
    const int w    = tid >> 6;
    const int lane = tid & 63;
    const int c    = lane & 15;
    const int quad = lane >> 4;
    const int j    = 16 * w + c;            // owned hidden unit (0..127)

    __shared__ __align__(16) _Float16 buf[2][192];          // [h(128); x(64)] f16, by step parity
    __shared__ __align__(16) float    xstage[2][16][STATE]; // fp32 x, by chunk parity
    __shared__ __align__(16) float    ring[2][16][HID];     // output ring, by chunk parity
    __shared__ float ms[32];                                // rolling mask window

    // ---- persistent B-fragments: rows j (r), 128+j (z), 256+j (n) ----
    const int rowb[3] = { j, HID + j, 2 * HID + j };
    half8 B[3][6];
#pragma unroll
    for (int ti = 0; ti < 3; ++ti) {
        const int g = rowb[ti];
#pragma unroll
        for (int kt = 0; kt < 6; ++kt) {
            const float* src = (kt < 4) ? (whh + (size_t)g * HID + kt * 32 + quad * 8)
                                        : (wih + (size_t)g * STATE + (kt - 4) * 32 + quad * 8);
            const float4 p0 = *(const float4*)(src);
            const float4 p1 = *(const float4*)(src + 4);
            half8 hb;
            hb[0] = (_Float16)p0.x; hb[1] = (_Float16)p0.y;
            hb[2] = (_Float16)p0.z; hb[3] = (_Float16)p0.w;
            hb[4] = (_Float16)p1.x; hb[5] = (_Float16)p1.y;
            hb[6] = (_Float16)p1.z; hb[7] = (_Float16)p1.w;
            B[ti][kt] = hb;
        }
    }

    // ---- biases for this lane's unit ----
    const float br  = bih[j] + bhh[j];
    const float bz  = bih[HID + j] + bhh[HID + j];
    const float bhn = bhh[2 * HID + j];
    const float bxn = bih[2 * HID + j];

    // ---- state / staging init ----
    float hr = h0[(size_t)b * HID + j];
    const float m0 = masks[b];
    float hm = m0 * hr;
    if (quad == 0) buf[0][j] = (_Float16)hm;
    if (tid < 32) {   // x_0 -> buf[0]
        const float2 xv = *(const float2*)(x + (size_t)b * STATE + 2 * tid);
        half2_t hx = { (_Float16)xv.x, (_Float16)xv.y };
        *(half2_t*)&buf[0][128 + 2 * tid] = hx;
    }
    float4 xp = {0.f, 0.f, 0.f, 0.f};
    if (tid < 256) {  // xstage[0] = x steps 1..16 ; xp = x steps 17..32
        const int k = tid >> 4, cc = (tid & 15) * 4;
        *(float4*)&xstage[0][k][cc] =
            *(const float4*)(x + ((size_t)(1 + k) * N_ENVS + b) * STATE + cc);
        xp = *(const float4*)(x + ((size_t)(17 + k) * N_ENVS + b) * STATE + cc);
    }
    float mreg = 0.f;
    if (tid < 16) {   // masks steps 0..15 in LDS; 16..31 in reg
        ms[tid] = masks[(size_t)tid * N_ENVS + b];
        mreg = masks[(size_t)(16 + tid) * N_ENVS + b];
    }
    __syncthreads();

    const floatx4 zero4 = {0.f, 0.f, 0.f, 0.f};

    for (int tc = 0; tc < 32; ++tc) {
        // ======== chunk-boundary VMEM (once per 16 steps) ========
        if (tc > 0) {   // flush previous chunk's outputs: 1 float4 per thread
            const int k = tid >> 5, jj = (tid & 31) * 4;
            *(float4*)(out + ((size_t)((tc - 1) * 16 + k) * N_ENVS + b) * HID + jj) =
                *(const float4*)&ring[(tc - 1) & 1][k][jj];
        }
        if (tid < 256) {  // xp (steps (tc+1)*16+1..+16) -> xstage for NEXT chunk
            const int k = tid >> 4, cc = (tid & 15) * 4;
            *(float4*)&xstage[(tc + 1) & 1][k][cc] = xp;
            const int st = (tc + 2) * 16 + 1 + k;   // reload for chunk tc+2
            if (st < T_STEPS)
                xp = *(const float4*)(x + ((size_t)st * N_ENVS + b) * STATE + cc);
        }
        if (tid < 16) {   // mask window roll
            ms[(tc * 16 + 16 + tid) & 31] = mreg;
            const int st = tc * 16 + 32 + tid;
            if (st < T_STEPS) mreg = masks[(size_t)st * N_ENVS + b];
        }

        // ======== 16 recurrence steps, one barrier each ========
#pragma unroll
        for (int s = 0; s < 16; ++s) {
            const int t = tc * 16 + s;
            const _Float16* bufc = buf[s & 1];
            _Float16* bufn = (_Float16*)buf[(s + 1) & 1];

            // A fragments: broadcast [h;x]
            half8 a0 = *(const half8*)(bufc + 0 * 32 + quad * 8);
            half8 a1 = *(const half8*)(bufc + 1 * 32 + quad * 8);
            half8 a2 = *(const half8*)(bufc + 2 * 32 + quad * 8);
            half8 a3 = *(const half8*)(bufc + 3 * 32 + quad * 8);
            half8 a4 = *(const half8*)(bufc + 4 * 32 + quad * 8);
            half8 a5 = *(const half8*)(bufc + 5 * 32 + quad * 8);

            // 18 MFMAs, 6 independent streams, max dep depth 4
            floatx4 r_a = __builtin_amdgcn_mfma_f32_16x16x32_f16(a0, B[0][0], zero4, 0, 0, 0);
            floatx4 r_b = __builtin_amdgcn_mfma_f32_16x16x32_f16(a3, B[0][3], zero4, 0, 0, 0);
            floatx4 z_a = __builtin_amdgcn_mfma_f32_16x16x32_f16(a0, B[1][0], zero4, 0, 0, 0);
            floatx4 z_b = __builtin_amdgcn_mfma_f32_16x16x32_f16(a3, B[1][3], zero4, 0, 0, 0);
            floatx4 hn4 = __builtin_amdgcn_mfma_f32_16x16x32_f16(a0, B[2][0], zero4, 0, 0, 0);
            floatx4 xn4 = __builtin_amdgcn_mfma_f32_16x16x32_f16(a4, B[2][4], zero4, 0, 0, 0);
            r_a = __builtin_amdgcn_mfma_f32_16x16x32_f16(a1, B[0][1], r_a, 0, 0, 0);
            r_b = __builtin_amdgcn_mfma_f32_16x16x32_f16(a4, B[0][4], r_b, 0, 0, 0);
            z_a = __builtin_amdgcn_mfma_f32_16x16x32_f16(a1, B[1][1], z_a, 0, 0, 0);
            z_b = __builtin_amdgcn_mfma_f32_16x16x32_f16(a4, B[1][4], z_b, 0, 0, 0);
            hn4 = __builtin_amdgcn_mfma_f32_16x16x32_f16(a1, B[2][1], hn4, 0, 0, 0);
            xn4 = __builtin_amdgcn_mfma_f32_16x16x32_f16(a5, B[2][5], xn4, 0, 0, 0);
            r_a = __builtin_amdgcn_mfma_f32_16x16x32_f16(a2, B[0][2], r_a, 0, 0, 0);
            r_b = __builtin_amdgcn_mfma_f32_16x16x32_f16(a5, B[0][5], r_b, 0, 0, 0);
            z_a = __builtin_amdgcn_mfma_f32_16x16x32_f16(a2, B[1][2], z_a, 0, 0, 0);
            z_b = __builtin_amdgcn_mfma_f32_16x16x32_f16(a5, B[1][5], z_b, 0, 0, 0);
            hn4 = __builtin_amdgcn_mfma_f32_16x16x32_f16(a2, B[2][2], hn4, 0, 0, 0);
            hn4 = __builtin_amdgcn_mfma_f32_16x16x32_f16(a3, B[2][3], hn4, 0, 0, 0);

            // gate math (3 transcendentals per lane)
            const float ur = (r_a[0] + r_b[0]) + br;
            const float uz = (z_a[0] + z_b[0]) + bz;
            const float hn = hn4[0] + bhn;
            const float xn = xn4[0] + bxn;
            const float r  = sigmoid_fast(ur);
            const float z  = sigmoid_fast(uz);
            const float cd = tanh_fast(fmaf(r, hn, xn));
            const float hnew = fmaf(z, hm - cd, cd);   // (1-z)*cand + z*(m*h)

            if (quad == 0) ring[tc & 1][s][j] = hnew;
            if (t < T_STEPS - 1) {
                const float mn = ms[(t + 1) & 31];
                hm = mn * hnew;
                if (quad == 0) bufn[j] = (_Float16)hm;          // masked h for next step
                if (w == (s & 7) && lane < 32) {                // x_{t+1} -> next buf
                    const float2 xv = *(const float2*)&xstage[tc & 1][s][2 * lane];
                    half2_t hx = { (_Float16)xv.x, (_Float16)xv.y };
                    *(half2_t*)&bufn[128 + 2 * lane] = hx;
                }
            }
            hr = hnew;
            __syncthreads();
        }
    }

    // final flush: chunk 31 (parity 1, steps 496..511)
    {
        const int k = tid >> 5, jj = (tid & 31) * 4;
        *(float4*)(out + ((size_t)(496 + k) * N_ENVS + b) * HID + jj) =
            *(const float4*)&ring[1][k][jj];
    }
    if (quad == 0)
        out[(size_t)T_STEPS * N_ENVS * HID + (size_t)b * HID + j] = hr;
}

extern "C" void kernel_launch(void* const* d_in, const int* in_sizes, int n_in,
                              void* d_out, int out_size, void* d_ws, size_t ws_size,
                              hipStream_t stream) {
    const float* x   = (const float*)d_in[0];
    const float* h0  = (const float*)d_in[1];
    const float* mk  = (const float*)d_in[2];
    const float* wih = (const float*)d_in[3];
    const float* whh = (const float*)d_in[4];
    const float* bih = (const float*)d_in[5];
    const float* bhh = (const float*)d_in[6];
    float* out = (float*)d_out;

    hipLaunchKernelGGL(gru_mfma8, dim3(N_ENVS), dim3(NTHREADS), 0, stream,
                       x, h0, mk, wih, whh, bih, bhh, out);
}

// Round 5
// 305.089 us; speedup vs baseline: 2.5733x; 1.1079x over previous
//
#include <hip/hip_runtime.h>
#include <math.h>

#define T_STEPS  512
#define N_ENVS   256
#define STATE    64
#define HID      128
#define NTHREADS 512   // 8 waves

typedef _Float16 half8   __attribute__((ext_vector_type(8)));
typedef _Float16 half4_t __attribute__((ext_vector_type(4)));
typedef float    floatx4 __attribute__((ext_vector_type(4)));

__device__ __forceinline__ float sigmoid_fast(float v) {
    return __builtin_amdgcn_rcpf(1.f + __expf(-v));
}
__device__ __forceinline__ float tanh_fast(float v) {
    const float e  = __expf(-2.f * fabsf(v));
    const float mg = (1.f - e) * __builtin_amdgcn_rcpf(1.f + e);
    return copysignf(mg, v);
}

// One block per env, 8 waves. Wave w owns gate rows j=16w+c for r (row j),
// z (row 128+j), n (row 256+j); lane c owns hidden unit j, quads redundant.
//
// R5: the x-projection gx = x . W_ih^T is time-parallel, so it is hoisted out
// of the recurrence and computed per 16-step chunk as a true M=16 MFMA GEMM
// (M carries timesteps; A-layout A[m=lane&15][k=quad*8+i], D row=quad*4+reg).
// gx is stored in LDS packed as gxp[s][j][{r,z,n,pad}] so each step needs ONE
// ds_read_b128 for all three x-gate terms. The recurrent step is then h-only
// K=128: 12 MFMAs/wave (96/CU ~466 cyc) + 4 broadcast A-frag b128 reads/wave.
__global__ __launch_bounds__(NTHREADS, 2) void gru_mfma_split(
    const float* __restrict__ x,      // (T*N, STATE)
    const float* __restrict__ h0,     // (N, HID)
    const float* __restrict__ masks,  // (T*N, 1) in {0,1}
    const float* __restrict__ wih,    // (3H, STATE)
    const float* __restrict__ whh,    // (3H, HID)
    const float* __restrict__ bih,    // (3H)
    const float* __restrict__ bhh,    // (3H)
    float* __restrict__ out)          // ys (T*N,H) then h_final (N,H)
{
    const int b    = blockIdx.x;
    const int tid  = threadIdx.x;
    const int w    = tid >> 6;
    const int lane = tid & 63;
    const int c    = lane & 15;
    const int quad = lane >> 4;
    const int j    = 16 * w + c;            // owned hidden unit (0..127)

    __shared__ __align__(16) _Float16 buf[2][HID];        // masked h f16, step parity
    __shared__ __align__(16) _Float16 xh[2][16][STATE];   // x f16 per chunk, chunk parity
    __shared__ __align__(16) float    gxp[16][HID][4];    // gx: [step][unit][{r,z,n,pad}]
    __shared__ __align__(16) float    ring[2][16][HID];   // output ring, chunk parity
    __shared__ float ms[32];                              // rolling mask window

    // ---- persistent W_hh B-fragments (K=128 -> 4 chunks) ----
    const int rowb[3] = { j, HID + j, 2 * HID + j };
    half8 Bh[3][4];
#pragma unroll
    for (int ti = 0; ti < 3; ++ti) {
        const int g = rowb[ti];
#pragma unroll
        for (int kt = 0; kt < 4; ++kt) {
            const float* src = whh + (size_t)g * HID + kt * 32 + quad * 8;
            const float4 p0 = *(const float4*)(src);
            const float4 p1 = *(const float4*)(src + 4);
            half8 hb;
            hb[0] = (_Float16)p0.x; hb[1] = (_Float16)p0.y;
            hb[2] = (_Float16)p0.z; hb[3] = (_Float16)p0.w;
            hb[4] = (_Float16)p1.x; hb[5] = (_Float16)p1.y;
            hb[6] = (_Float16)p1.z; hb[7] = (_Float16)p1.w;
            Bh[ti][kt] = hb;
        }
    }
    // ---- persistent W_ih B-fragments (K=64 -> 2 chunks) ----
    half8 Bx[3][2];
#pragma unroll
    for (int ti = 0; ti < 3; ++ti) {
        const int g = rowb[ti];
#pragma unroll
        for (int kt = 0; kt < 2; ++kt) {
            const float* src = wih + (size_t)g * STATE + kt * 32 + quad * 8;
            const float4 p0 = *(const float4*)(src);
            const float4 p1 = *(const float4*)(src + 4);
            half8 hb;
            hb[0] = (_Float16)p0.x; hb[1] = (_Float16)p0.y;
            hb[2] = (_Float16)p0.z; hb[3] = (_Float16)p0.w;
            hb[4] = (_Float16)p1.x; hb[5] = (_Float16)p1.y;
            hb[6] = (_Float16)p1.z; hb[7] = (_Float16)p1.w;
            Bx[ti][kt] = hb;
        }
    }

    const float br  = bih[j] + bhh[j];
    const float bz  = bih[HID + j] + bhh[HID + j];
    const float bhn = bhh[2 * HID + j];
    const float bxn = bih[2 * HID + j];

    // ---- state / staging init ----
    float hr = h0[(size_t)b * HID + j];
    const float m0 = masks[b];
    float hm = m0 * hr;
    if (quad == 0) buf[0][j] = (_Float16)hm;

    float4 xp = {0.f, 0.f, 0.f, 0.f};
    if (tid < 256) {   // xh[0] = x steps 0..15 ; xp = x steps 16..31
        const int k = tid >> 4, cc = (tid & 15) * 4;
        const float4 xv = *(const float4*)(x + ((size_t)k * N_ENVS + b) * STATE + cc);
        half4_t hx = {(_Float16)xv.x, (_Float16)xv.y, (_Float16)xv.z, (_Float16)xv.w};
        *(half4_t*)&xh[0][k][cc] = hx;
        xp = *(const float4*)(x + ((size_t)(16 + k) * N_ENVS + b) * STATE + cc);
    }
    float mreg = 0.f;
    if (tid < 16) {
        ms[tid] = masks[(size_t)tid * N_ENVS + b];
        mreg = masks[(size_t)(16 + tid) * N_ENVS + b];
    }
    __syncthreads();   // xh[0] + buf[0] visible

    const floatx4 zero4 = {0.f, 0.f, 0.f, 0.f};

    for (int tc = 0; tc < 32; ++tc) {
        // ======== chunk boundary (once per 16 steps) ========
        if (tc > 0) {   // flush previous chunk's outputs
            const int k = tid >> 5, jj = (tid & 31) * 4;
            *(float4*)(out + ((size_t)((tc - 1) * 16 + k) * N_ENVS + b) * HID + jj) =
                *(const float4*)&ring[(tc - 1) & 1][k][jj];
        }
        if (tid < 256) {   // xp (steps (tc+1)*16..+15) -> xh for next chunk
            const int k = tid >> 4, cc = (tid & 15) * 4;
            half4_t hx = {(_Float16)xp.x, (_Float16)xp.y, (_Float16)xp.z, (_Float16)xp.w};
            *(half4_t*)&xh[(tc + 1) & 1][k][cc] = hx;
            const int st = (tc + 2) * 16 + k;
            if (st < T_STEPS)
                xp = *(const float4*)(x + ((size_t)st * N_ENVS + b) * STATE + cc);
        }
        if (tid < 16) {    // mask window roll
            ms[(tc * 16 + 16 + tid) & 31] = mreg;
            const int st = tc * 16 + 32 + tid;
            if (st < T_STEPS) mreg = masks[(size_t)st * N_ENVS + b];
        }

        // batched x-projection GEMM for this chunk: gx[s][row] for s=0..15
        {
            const _Float16* xr = &xh[tc & 1][c][0];   // A row m=c : x[step c][*]
            half8 ax0 = *(const half8*)&xr[quad * 8];        // features 0..31 chunk
            half8 ax1 = *(const half8*)&xr[32 + quad * 8];   // features 32..63 chunk
            floatx4 g0 = __builtin_amdgcn_mfma_f32_16x16x32_f16(ax0, Bx[0][0], zero4, 0, 0, 0);
            floatx4 g1 = __builtin_amdgcn_mfma_f32_16x16x32_f16(ax0, Bx[1][0], zero4, 0, 0, 0);
            floatx4 g2 = __builtin_amdgcn_mfma_f32_16x16x32_f16(ax0, Bx[2][0], zero4, 0, 0, 0);
            g0 = __builtin_amdgcn_mfma_f32_16x16x32_f16(ax1, Bx[0][1], g0, 0, 0, 0);
            g1 = __builtin_amdgcn_mfma_f32_16x16x32_f16(ax1, Bx[1][1], g1, 0, 0, 0);
            g2 = __builtin_amdgcn_mfma_f32_16x16x32_f16(ax1, Bx[2][1], g2, 0, 0, 0);
            // D[step = quad*4 + i][col = c] -> gxp[step][j][gate]
#pragma unroll
            for (int i = 0; i < 4; ++i) {
                const int s4 = quad * 4 + i;
                gxp[s4][j][0] = g0[i];
                gxp[s4][j][1] = g1[i];
                gxp[s4][j][2] = g2[i];
            }
        }
        __syncthreads();

        // ======== 16 recurrence steps, one barrier each ========
#pragma unroll
        for (int s = 0; s < 16; ++s) {
            const int t = tc * 16 + s;
            const _Float16* bufc = buf[s & 1];
            _Float16* bufn = (_Float16*)buf[(s + 1) & 1];

            // A fragments: broadcast masked h (4 K-chunks of 32)
            half8 a0 = *(const half8*)(bufc + 0 * 32 + quad * 8);
            half8 a1 = *(const half8*)(bufc + 1 * 32 + quad * 8);
            half8 a2 = *(const half8*)(bufc + 2 * 32 + quad * 8);
            half8 a3 = *(const half8*)(bufc + 3 * 32 + quad * 8);

            // 12 MFMAs, 6 independent streams of depth 2
            floatx4 r_a = __builtin_amdgcn_mfma_f32_16x16x32_f16(a0, Bh[0][0], zero4, 0, 0, 0);
            floatx4 r_b = __builtin_amdgcn_mfma_f32_16x16x32_f16(a2, Bh[0][2], zero4, 0, 0, 0);
            floatx4 z_a = __builtin_amdgcn_mfma_f32_16x16x32_f16(a0, Bh[1][0], zero4, 0, 0, 0);
            floatx4 z_b = __builtin_amdgcn_mfma_f32_16x16x32_f16(a2, Bh[1][2], zero4, 0, 0, 0);
            floatx4 n_a = __builtin_amdgcn_mfma_f32_16x16x32_f16(a0, Bh[2][0], zero4, 0, 0, 0);
            floatx4 n_b = __builtin_amdgcn_mfma_f32_16x16x32_f16(a2, Bh[2][2], zero4, 0, 0, 0);
            r_a = __builtin_amdgcn_mfma_f32_16x16x32_f16(a1, Bh[0][1], r_a, 0, 0, 0);
            r_b = __builtin_amdgcn_mfma_f32_16x16x32_f16(a3, Bh[0][3], r_b, 0, 0, 0);
            z_a = __builtin_amdgcn_mfma_f32_16x16x32_f16(a1, Bh[1][1], z_a, 0, 0, 0);
            z_b = __builtin_amdgcn_mfma_f32_16x16x32_f16(a3, Bh[1][3], z_b, 0, 0, 0);
            n_a = __builtin_amdgcn_mfma_f32_16x16x32_f16(a1, Bh[2][1], n_a, 0, 0, 0);
            n_b = __builtin_amdgcn_mfma_f32_16x16x32_f16(a3, Bh[2][3], n_b, 0, 0, 0);

            // x-gate terms: one b128 per lane (broadcast across quads)
            const float4 gx4 = *(const float4*)&gxp[s][j][0];

            const float ur = (r_a[0] + r_b[0]) + gx4.x + br;
            const float uz = (z_a[0] + z_b[0]) + gx4.y + bz;
            const float hn = (n_a[0] + n_b[0]) + bhn;
            const float xn = gx4.z + bxn;
            const float r  = sigmoid_fast(ur);
            const float z  = sigmoid_fast(uz);
            const float cd = tanh_fast(fmaf(r, hn, xn));
            const float hnew = fmaf(z, hm - cd, cd);   // (1-z)*cand + z*(m*h)

            if (quad == 0) ring[tc & 1][s][j] = hnew;
            if (t < T_STEPS - 1) {
                const float mn = ms[(t + 1) & 31];
                hm = mn * hnew;
                if (quad == 0) bufn[j] = (_Float16)hm;
            }
            hr = hnew;
            __syncthreads();
        }
    }

    // final flush: chunk 31 (parity 1, steps 496..511)
    {
        const int k = tid >> 5, jj = (tid & 31) * 4;
        *(float4*)(out + ((size_t)(496 + k) * N_ENVS + b) * HID + jj) =
            *(const float4*)&ring[1][k][jj];
    }
    if (quad == 0)
        out[(size_t)T_STEPS * N_ENVS * HID + (size_t)b * HID + j] = hr;
}

extern "C" void kernel_launch(void* const* d_in, const int* in_sizes, int n_in,
                              void* d_out, int out_size, void* d_ws, size_t ws_size,
                              hipStream_t stream) {
    const float* x   = (const float*)d_in[0];
    const float* h0  = (const float*)d_in[1];
    const float* mk  = (const float*)d_in[2];
    const float* wih = (const float*)d_in[3];
    const float* whh = (const float*)d_in[4];
    const float* bih = (const float*)d_in[5];
    const float* bhh = (const float*)d_in[6];
    float* out = (float*)d_out;

    hipLaunchKernelGGL(gru_mfma_split, dim3(N_ENVS), dim3(NTHREADS), 0, stream,
                       x, h0, mk, wih, whh, bih, bhh, out);
}

// Round 6
// 291.723 us; speedup vs baseline: 2.6912x; 1.0458x over previous
//
#include <hip/hip_runtime.h>
#include <math.h>

#define T_STEPS  512
#define N_ENVS   256
#define STATE    64
#define HID      128
#define NTHREADS 512   // 8 waves
#define XPAD     72    // xh row stride in f16 (64 + 8 pad: breaks 16-way bank conflict)

typedef _Float16 half8   __attribute__((ext_vector_type(8)));
typedef _Float16 half4_t __attribute__((ext_vector_type(4)));
typedef float    floatx4 __attribute__((ext_vector_type(4)));

// One block per env, 8 waves. Wave w owns gate rows j=16w+c for r (row j),
// z (row 128+j), n (row 256+j); lane c owns hidden unit j, quads redundant.
//
// R6 phase-shrink (per-step critical path was LDS + MFMA + VALU, phase-locked
// at the barrier):
//  - outputs in 4 regs/lane (quad-striped steps), bulk global store per chunk
//    (no ring LDS write per step, no flush LDS reads)
//  - masks via per-lane register window + v_readlane (no ms[] LDS read)
//  - gx staged as packed f16 half4 (biases folded) -> one ds_read_b64/step
//  - gate math with 3 exp + 2 rcp: h' = [s_a*e_z*(1-e_t) + hm*(1+e_t)] /
//    [(1+e_t)*(1+e_z)]  (z's rcp fused into the update rcp)
__global__ __launch_bounds__(NTHREADS, 2) void gru_r6(
    const float* __restrict__ x,      // (T*N, STATE)
    const float* __restrict__ h0,     // (N, HID)
    const float* __restrict__ masks,  // (T*N, 1) in {0,1}
    const float* __restrict__ wih,    // (3H, STATE)
    const float* __restrict__ whh,    // (3H, HID)
    const float* __restrict__ bih,    // (3H)
    const float* __restrict__ bhh,    // (3H)
    float* __restrict__ out)          // ys (T*N,H) then h_final (N,H)
{
    const int b    = blockIdx.x;
    const int tid  = threadIdx.x;
    const int w    = tid >> 6;
    const int lane = tid & 63;
    const int c    = lane & 15;
    const int quad = lane >> 4;
    const int j    = 16 * w + c;            // owned hidden unit (0..127)

    __shared__ __align__(16) _Float16 buf[2][HID];        // masked h f16, step parity
    __shared__ __align__(16) _Float16 xh[2][16][XPAD];    // x f16 per chunk (padded rows)
    __shared__ __align__(16) _Float16 gxp[16][HID][4];    // gx+bias: [step][unit][{r,z,n,pad}] f16

    // ---- persistent W_hh B-fragments (K=128 -> 4 chunks) ----
    const int rowb[3] = { j, HID + j, 2 * HID + j };
    half8 Bh[3][4];
#pragma unroll
    for (int ti = 0; ti < 3; ++ti) {
        const int g = rowb[ti];
#pragma unroll
        for (int kt = 0; kt < 4; ++kt) {
            const float* src = whh + (size_t)g * HID + kt * 32 + quad * 8;
            const float4 p0 = *(const float4*)(src);
            const float4 p1 = *(const float4*)(src + 4);
            half8 hb;
            hb[0] = (_Float16)p0.x; hb[1] = (_Float16)p0.y;
            hb[2] = (_Float16)p0.z; hb[3] = (_Float16)p0.w;
            hb[4] = (_Float16)p1.x; hb[5] = (_Float16)p1.y;
            hb[6] = (_Float16)p1.z; hb[7] = (_Float16)p1.w;
            Bh[ti][kt] = hb;
        }
    }
    // ---- persistent W_ih B-fragments (K=64 -> 2 chunks) ----
    half8 Bx[3][2];
#pragma unroll
    for (int ti = 0; ti < 3; ++ti) {
        const int g = rowb[ti];
#pragma unroll
        for (int kt = 0; kt < 2; ++kt) {
            const float* src = wih + (size_t)g * STATE + kt * 32 + quad * 8;
            const float4 p0 = *(const float4*)(src);
            const float4 p1 = *(const float4*)(src + 4);
            half8 hb;
            hb[0] = (_Float16)p0.x; hb[1] = (_Float16)p0.y;
            hb[2] = (_Float16)p0.z; hb[3] = (_Float16)p0.w;
            hb[4] = (_Float16)p1.x; hb[5] = (_Float16)p1.y;
            hb[6] = (_Float16)p1.z; hb[7] = (_Float16)p1.w;
            Bx[ti][kt] = hb;
        }
    }

    const float br  = bih[j] + bhh[j];                    // r: folded into gxp
    const float bz  = bih[HID + j] + bhh[HID + j];        // z: folded into gxp
    const float bxn = bih[2 * HID + j];                   // xn: folded into gxp
    const float bhn = bhh[2 * HID + j];                   // hn: applied per step

    // ---- state / staging init ----
    float hr = h0[(size_t)b * HID + j];
    float hm = masks[b] * hr;
    if (quad == 0) buf[0][j] = (_Float16)hm;

    float4 xp = {0.f, 0.f, 0.f, 0.f};
    if (tid < 256) {   // xh[0] = x steps 0..15 ; xp = x steps 16..31
        const int k = tid >> 4, cc = (tid & 15) * 4;
        const float4 xv = *(const float4*)(x + ((size_t)k * N_ENVS + b) * STATE + cc);
        half4_t hx = {(_Float16)xv.x, (_Float16)xv.y, (_Float16)xv.z, (_Float16)xv.w};
        *(half4_t*)&xh[0][k][cc] = hx;
        xp = *(const float4*)(x + ((size_t)(16 + k) * N_ENVS + b) * STATE + cc);
    }
    // mask windows: lane l holds masks[tb+1+l] for current chunk (l = lane&15)
    float mwin  = masks[(size_t)(1  + (lane & 15)) * N_ENVS + b];
    float mwin_nxt = masks[(size_t)(17 + (lane & 15)) * N_ENVS + b];

    float o[4] = {0.f, 0.f, 0.f, 0.f};   // output regs: step s=quad*4+i -> o[i]

    __syncthreads();   // xh[0] + buf[0] visible

    const floatx4 zero4 = {0.f, 0.f, 0.f, 0.f};

    for (int tc = 0; tc < 32; ++tc) {
        // ======== chunk boundary (once per 16 steps) ========
        if (tc > 0) {   // store previous chunk's outputs straight from registers
            const int tbp = (tc - 1) * 16;
#pragma unroll
            for (int i = 0; i < 4; ++i)
                out[((size_t)(tbp + quad * 4 + i) * N_ENVS + b) * HID + j] = o[i];
            // roll mask window
            mwin = mwin_nxt;
            const int stm = (tc + 1) * 16 + 1 + (lane & 15);
            mwin_nxt = masks[(size_t)(stm < T_STEPS ? stm : T_STEPS - 1) * N_ENVS + b];
        }
        if (tid < 256) {   // xp (steps (tc+1)*16..+15) -> xh for next chunk
            const int k = tid >> 4, cc = (tid & 15) * 4;
            half4_t hx = {(_Float16)xp.x, (_Float16)xp.y, (_Float16)xp.z, (_Float16)xp.w};
            *(half4_t*)&xh[(tc + 1) & 1][k][cc] = hx;
            const int st = (tc + 2) * 16 + k;
            if (st < T_STEPS)
                xp = *(const float4*)(x + ((size_t)st * N_ENVS + b) * STATE + cc);
        }

        // batched x-projection GEMM for this chunk: A row m=c is x[step tb+c][*]
        {
            const _Float16* xr = &xh[tc & 1][c][0];
            half8 ax0 = *(const half8*)&xr[quad * 8];
            half8 ax1 = *(const half8*)&xr[32 + quad * 8];
            floatx4 g0 = __builtin_amdgcn_mfma_f32_16x16x32_f16(ax0, Bx[0][0], zero4, 0, 0, 0);
            floatx4 g1 = __builtin_amdgcn_mfma_f32_16x16x32_f16(ax0, Bx[1][0], zero4, 0, 0, 0);
            floatx4 g2 = __builtin_amdgcn_mfma_f32_16x16x32_f16(ax0, Bx[2][0], zero4, 0, 0, 0);
            g0 = __builtin_amdgcn_mfma_f32_16x16x32_f16(ax1, Bx[0][1], g0, 0, 0, 0);
            g1 = __builtin_amdgcn_mfma_f32_16x16x32_f16(ax1, Bx[1][1], g1, 0, 0, 0);
            g2 = __builtin_amdgcn_mfma_f32_16x16x32_f16(ax1, Bx[2][1], g2, 0, 0, 0);
            // D[step=quad*4+i][col=c] -> packed f16 {r,z,n,pad} with biases folded
#pragma unroll
            for (int i = 0; i < 4; ++i) {
                half4_t p;
                p[0] = (_Float16)(g0[i] + br);
                p[1] = (_Float16)(g1[i] + bz);
                p[2] = (_Float16)(g2[i] + bxn);
                p[3] = (_Float16)0.f;
                *(half4_t*)&gxp[quad * 4 + i][j][0] = p;
            }
        }
        __syncthreads();

        // ======== 16 recurrence steps, one barrier each ========
#pragma unroll
        for (int s = 0; s < 16; ++s) {
            const int t = tc * 16 + s;
            const _Float16* bufc = buf[s & 1];
            _Float16* bufn = (_Float16*)buf[(s + 1) & 1];

            // A fragments: broadcast masked h (4 K-chunks of 32)
            half8 a0 = *(const half8*)(bufc + 0 * 32 + quad * 8);
            half8 a1 = *(const half8*)(bufc + 1 * 32 + quad * 8);
            half8 a2 = *(const half8*)(bufc + 2 * 32 + quad * 8);
            half8 a3 = *(const half8*)(bufc + 3 * 32 + quad * 8);
            // x-gate terms: one b64 per lane (broadcast across quads)
            const half4_t gxh = *(const half4_t*)&gxp[s][j][0];

            // 12 MFMAs, 6 independent streams of depth 2
            floatx4 r_a = __builtin_amdgcn_mfma_f32_16x16x32_f16(a0, Bh[0][0], zero4, 0, 0, 0);
            floatx4 r_b = __builtin_amdgcn_mfma_f32_16x16x32_f16(a2, Bh[0][2], zero4, 0, 0, 0);
            floatx4 z_a = __builtin_amdgcn_mfma_f32_16x16x32_f16(a0, Bh[1][0], zero4, 0, 0, 0);
            floatx4 z_b = __builtin_amdgcn_mfma_f32_16x16x32_f16(a2, Bh[1][2], zero4, 0, 0, 0);
            floatx4 n_a = __builtin_amdgcn_mfma_f32_16x16x32_f16(a0, Bh[2][0], zero4, 0, 0, 0);
            floatx4 n_b = __builtin_amdgcn_mfma_f32_16x16x32_f16(a2, Bh[2][2], zero4, 0, 0, 0);
            r_a = __builtin_amdgcn_mfma_f32_16x16x32_f16(a1, Bh[0][1], r_a, 0, 0, 0);
            r_b = __builtin_amdgcn_mfma_f32_16x16x32_f16(a3, Bh[0][3], r_b, 0, 0, 0);
            z_a = __builtin_amdgcn_mfma_f32_16x16x32_f16(a1, Bh[1][1], z_a, 0, 0, 0);
            z_b = __builtin_amdgcn_mfma_f32_16x16x32_f16(a3, Bh[1][3], z_b, 0, 0, 0);
            n_a = __builtin_amdgcn_mfma_f32_16x16x32_f16(a1, Bh[2][1], n_a, 0, 0, 0);
            n_b = __builtin_amdgcn_mfma_f32_16x16x32_f16(a3, Bh[2][3], n_b, 0, 0, 0);

            const float ur = (r_a[0] + r_b[0]) + (float)gxh[0];   // incl. br
            const float uz = (z_a[0] + z_b[0]) + (float)gxh[1];   // incl. bz
            const float hn = (n_a[0] + n_b[0]) + bhn;
            const float xn = (float)gxh[2];                        // incl. bxn

            // 3 exp + 2 rcp gate math:
            // r = sigma(ur); a = xn + r*hn; t = tanh(a); z = sigma(uz)
            // h' = [sign(a)*e_z*(1-e_t) + hm*(1+e_t)] / [(1+e_t)*(1+e_z)]
            const float e_r = __expf(-ur);                         // inf-safe: rcp(inf)=0
            const float r   = __builtin_amdgcn_rcpf(1.f + e_r);
            const float a   = fmaf(r, hn, xn);
            const float e_t = __expf(-2.f * fabsf(a));             // (0,1]
            const float e_z = __expf(-fmaxf(uz, -30.f));           // <= e^30, finite
            const float opt = 1.f + e_t;
            float num = copysignf(e_z * (1.f - e_t), a);
            num = fmaf(hm, opt, num);
            const float den = opt * (1.f + e_z);
            const float hnew = num * __builtin_amdgcn_rcpf(den);

            o[s & 3] = (quad == (s >> 2)) ? hnew : o[s & 3];       // quad-striped output regs

            if (t < T_STEPS - 1) {
                const int   mi = __builtin_amdgcn_readlane(__float_as_int(mwin), s);
                const float mn = __int_as_float(mi);               // masks[t+1], uniform
                hm = mn * hnew;
                if (quad == 0) bufn[j] = (_Float16)hm;             // masked h for next step
            }
            hr = hnew;
            __syncthreads();
        }
    }

    // final flush: chunk 31 from registers
    {
        const int tbp = 31 * 16;
#pragma unroll
        for (int i = 0; i < 4; ++i)
            out[((size_t)(tbp + quad * 4 + i) * N_ENVS + b) * HID + j] = o[i];
    }
    if (quad == 0)
        out[(size_t)T_STEPS * N_ENVS * HID + (size_t)b * HID + j] = hr;
}

extern "C" void kernel_launch(void* const* d_in, const int* in_sizes, int n_in,
                              void* d_out, int out_size, void* d_ws, size_t ws_size,
                              hipStream_t stream) {
    const float* x   = (const float*)d_in[0];
    const float* h0  = (const float*)d_in[1];
    const float* mk  = (const float*)d_in[2];
    const float* wih = (const float*)d_in[3];
    const float* whh = (const float*)d_in[4];
    const float* bih = (const float*)d_in[5];
    const float* bhh = (const float*)d_in[6];
    float* out = (float*)d_out;

    hipLaunchKernelGGL(gru_r6, dim3(N_ENVS), dim3(NTHREADS), 0, stream,
                       x, h0, mk, wih, whh, bih, bhh, out);
}